// Round 10
// baseline (195.681 us; speedup 1.0000x reference)
//
#include <hip/hip_runtime.h>
#include <math.h>

#define SEQ_LENGTH 4096
#define D_MODEL   2048
#define BATCH     32
#define TABLE_F4  (SEQ_LENGTH * D_MODEL / 4)   // 2^21 float4s per batch copy
#define TOTAL_F4  (BATCH * TABLE_F4)           // 2^26 float4s total
#define IT        16                           // float4s per thread (64 KiB/block)
#define NWG       (TOTAL_F4 / (256 * IT))      // 16384 blocks (divisible by 8)

typedef float f4 __attribute__((ext_vector_type(4)));

// Output [B, S, D]: pe[s,2i] = sin(s * 10000^(-2i/D)), pe[s,2i+1] = cos(...),
// broadcast over B.
// Structure (R6+R8 ladder): short-lived blocks writing contiguous chunks
// (beats persistent grid-stride — R7 drift kills DRAM page locality) +
// XCD-bijective swizzle (each XCD owns a contiguous 1/8 -> long sequential
// L2 writeback streams; 5.45 -> 6.10 TB/s). This round: 64 KiB/block +
// nt-stores for the write-once-never-read output.
//
// NOTE: direct exp2 for both pairs — an f0*ratio recurrence loses 5.5e-6
// relative freq accuracy -> 0.023 absmax at s=4095 (R5 failure).
__global__ __launch_bounds__(256) void PositionalEncoding_54915451847173_kernel(
    float* __restrict__ out) {
    const int bid  = blockIdx.x;
    const int swz  = (bid & 7) * (NWG >> 3) + (bid >> 3);
    const int base = swz * (256 * IT) + threadIdx.x;

    const float c      = -(2.0f / (float)D_MODEL) * 13.28771237954945f; // -2/D*log2(1e4)
    const float inv2pi = 0.15915494309189535f;

    #pragma unroll
    for (int it = 0; it < IT; ++it) {
        const int u  = base + it * 256;         // f4 index in output
        const int t  = u & (TABLE_F4 - 1);      // index within the [S,D] table
        const int jj = t & (D_MODEL / 4 - 1);   // float4 within row, 0..511
        const int s  = t >> 9;                  // seq position (D/4 = 512)

        const float pos = (float)s;
        const float f0 = __builtin_amdgcn_exp2f(c * (float)(2 * jj));
        const float f1 = __builtin_amdgcn_exp2f(c * (float)(2 * jj + 1));

        // v_sin/v_cos take REVOLUTIONS; explicit v_fract range reduction.
        const float r0 = __builtin_amdgcn_fractf(pos * (f0 * inv2pi));
        const float r1 = __builtin_amdgcn_fractf(pos * (f1 * inv2pi));

        f4 v;
        v.x = __builtin_amdgcn_sinf(r0);
        v.y = __builtin_amdgcn_cosf(r0);
        v.z = __builtin_amdgcn_sinf(r1);
        v.w = __builtin_amdgcn_cosf(r1);

        __builtin_nontemporal_store(v, (f4*)out + u);
    }
}

extern "C" void kernel_launch(void* const* d_in, const int* in_sizes, int n_in,
                              void* d_out, int out_size, void* d_ws, size_t ws_size,
                              hipStream_t stream) {
    (void)d_in; (void)in_sizes; (void)n_in; (void)d_ws; (void)ws_size; (void)out_size;
    float* out = (float*)d_out;
    PositionalEncoding_54915451847173_kernel<<<NWG, 256, 0, stream>>>(out);
}

// Round 11
// 175.673 us; speedup vs baseline: 1.1139x; 1.1139x over previous
//
#include <hip/hip_runtime.h>
#include <math.h>

#define SEQ_LENGTH 4096
#define D_MODEL   2048
#define BATCH     32
#define TABLE_F4  (SEQ_LENGTH * D_MODEL / 4)   // 2^21 float4s per batch copy
#define TOTAL_F4  (BATCH * TABLE_F4)           // 2^26 float4s total
#define IT        8                            // float4s per thread (32 KiB/block)
#define NWG       (TOTAL_F4 / (256 * IT))      // 32768 blocks (divisible by 8)

typedef float f4 __attribute__((ext_vector_type(4)));

// Output [B, S, D]: pe[s,2i] = sin(s * 10000^(-2i/D)), pe[s,2i+1] = cos(...),
// broadcast over B. FINAL (R8 config, 176 us = 6.10 TB/s writes):
//  - short-lived blocks, each writing one contiguous 32 KiB chunk
//    (beats persistent grid-stride: R7 showed wave drift kills DRAM page
//    locality, 249 us; beats 32-way strided batch broadcast: R1, 236 us)
//  - XCD-bijective swizzle: each of the 8 XCDs owns one contiguous 1/8 of
//    the output -> long sequential per-L2 writeback streams (197 -> 176 us)
//  - plain cached stores (nt-stores + 64 KiB blocks regressed to 196 us, R10)
//  - trig recomputed per element: ~7 transcendental ops per 16B is far above
//    the 6.5 TB/s store ceiling, fully hidden under the write stream
//  - direct exp2 for BOTH pair frequencies — an f0*ratio recurrence loses
//    5.5e-6 relative accuracy -> 0.023 absmax at s=4095 (R5 failure)
__global__ __launch_bounds__(256) void PositionalEncoding_54915451847173_kernel(
    float* __restrict__ out) {
    const int bid  = blockIdx.x;
    const int swz  = (bid & 7) * (NWG >> 3) + (bid >> 3);
    const int base = swz * (256 * IT) + threadIdx.x;

    const float c      = -(2.0f / (float)D_MODEL) * 13.28771237954945f; // -2/D*log2(1e4)
    const float inv2pi = 0.15915494309189535f;

    #pragma unroll
    for (int it = 0; it < IT; ++it) {
        const int u  = base + it * 256;         // f4 index in output
        const int t  = u & (TABLE_F4 - 1);      // index within the [S,D] table
        const int jj = t & (D_MODEL / 4 - 1);   // float4 within row, 0..511
        const int s  = t >> 9;                  // seq position (D/4 = 512)

        const float pos = (float)s;
        const float f0 = __builtin_amdgcn_exp2f(c * (float)(2 * jj));
        const float f1 = __builtin_amdgcn_exp2f(c * (float)(2 * jj + 1));

        // v_sin/v_cos take REVOLUTIONS; explicit v_fract range reduction.
        const float r0 = __builtin_amdgcn_fractf(pos * (f0 * inv2pi));
        const float r1 = __builtin_amdgcn_fractf(pos * (f1 * inv2pi));

        f4 v;
        v.x = __builtin_amdgcn_sinf(r0);
        v.y = __builtin_amdgcn_cosf(r0);
        v.z = __builtin_amdgcn_sinf(r1);
        v.w = __builtin_amdgcn_cosf(r1);

        ((f4*)out)[u] = v;
    }
}

extern "C" void kernel_launch(void* const* d_in, const int* in_sizes, int n_in,
                              void* d_out, int out_size, void* d_ws, size_t ws_size,
                              hipStream_t stream) {
    (void)d_in; (void)in_sizes; (void)n_in; (void)d_ws; (void)ws_size; (void)out_size;
    float* out = (float*)d_out;
    PositionalEncoding_54915451847173_kernel<<<NWG, 256, 0, stream>>>(out);
}